// Round 13
// baseline (173.268 us; speedup 1.0000x reference)
//
#include <hip/hip_runtime.h>

// Output layout: dw1[12][24] at out[0..288), dw2[24][24] at out[288..864),
// s0[B][12] at out+864, s1[B][24] after s0.

typedef __bf16 bf16x8 __attribute__((ext_vector_type(8)));
typedef float  f32x4  __attribute__((ext_vector_type(4)));

constexpr int TPB = 256;           // 4 waves; each wave owns 64 rows per block-tile
constexpr int LDSS = 72;           // LDS row stride (elems): 144B, conflict-benign frag reads

__global__ void zero_dw_kernel(float* out) {
    int t = threadIdx.x + blockIdx.x * blockDim.x;
    if (t < 864) out[t] = 0.0f;
}

__global__ __launch_bounds__(TPB, 3)
void bnesnn_kernel(const float* __restrict__ x1, const float* __restrict__ x2,
                   const float* __restrict__ W0, const float* __restrict__ W1,
                   const float* __restrict__ W2, float* __restrict__ out, int B)
{
    // Per-wave private slices: aT rows 0..11 = s0 spikes, 12..35 = x2 vals, 36..47 = pad;
    // bT rows 0..23 = s1 spikes, 24..31 = pad. No cross-wave coupling -> no loop barriers.
    __shared__ __attribute__((aligned(16))) __bf16 aT[4 * 48 * LDSS];
    __shared__ __attribute__((aligned(16))) __bf16 bT[4 * 32 * LDSS];

    const int tid = threadIdx.x;
    const int w   = tid >> 6;
    const int l   = tid & 63;
    __bf16* aTw = aT + w * 48 * LDSS;
    __bf16* bTw = bT + w * 32 * LDSS;

    // Zero own pad rows once (wave-private).
    for (int i = l; i < 12 * LDSS; i += 64) aTw[36 * LDSS + i] = (__bf16)0.0f;
    for (int i = l; i <  8 * LDSS; i += 64) bTw[24 * LDSS + i] = (__bf16)0.0f;

    // Structure detection: W0 diag, W1 zero, W2 diag (uniform, deterministic).
    bool okv = true;
    for (int i = tid; i < 144; i += TPB) if ((i / 12) != (i % 12) && W0[i] != 0.0f) okv = false;
    for (int i = tid; i < 288; i += TPB) if (W1[i] != 0.0f) okv = false;
    for (int i = tid; i < 576; i += TPB) if ((i / 24) != (i % 24) && W2[i] != 0.0f) okv = false;
    const int fast = __syncthreads_and(okv ? 1 : 0);

    float* s0out = out + 864;
    float* s1out = out + 864 + (size_t)12 * B;

    const int lrow = l & 15;
    const int kb   = (l >> 4) * 8;

    f32x4 acc[6] = {};   // all 6 output positions per wave (statically indexed)

    const int NT = (B + 255) / 256;

    // Balanced contiguous chunk per block: adjacent tiles -> prefetch is 36KB ahead.
    const int grid = gridDim.x;
    const int qn = NT / grid, rn = NT % grid;
    const int bid = blockIdx.x;
    const int t0  = (bid < rn) ? bid * (qn + 1) : rn * (qn + 1) + (bid - rn) * qn;
    const int t1  = t0 + ((bid < rn) ? qn + 1 : qn);

    auto mfmaPhase = [&]() {
        #pragma unroll
        for (int p = 0; p < 6; ++p) {
            const int mt = p % 3, nt = p / 3;
            const int ar = (mt * 16 + lrow) * LDSS + kb;
            const int br = (nt * 16 + lrow) * LDSS + kb;
            #pragma unroll
            for (int kk = 0; kk < 64; kk += 32) {
                bf16x8 af = *(const bf16x8*)&aTw[ar + kk];
                bf16x8 bf = *(const bf16x8*)&bTw[br + kk];
                acc[p] = __builtin_amdgcn_mfma_f32_16x16x32_bf16(af, bf, acc[p], 0, 0, 0);
            }
        }
    };

    if (fast) {
        // Diagonal chunk vectors (uniform scalar loads), then per-lane selection.
        f32x4 D0[3], D2[6];
        #pragma unroll
        for (int c = 0; c < 3; ++c) {
            D0[c][0] = W0[(4*c+0)*13]; D0[c][1] = W0[(4*c+1)*13];
            D0[c][2] = W0[(4*c+2)*13]; D0[c][3] = W0[(4*c+3)*13];
        }
        #pragma unroll
        for (int c = 0; c < 6; ++c) {
            D2[c][0] = W2[(4*c+0)*25]; D2[c][1] = W2[(4*c+1)*25];
            D2[c][2] = W2[(4*c+2)*25]; D2[c][3] = W2[(4*c+3)*25];
        }
        const int t3 = l % 3, t6 = l % 6;
        f32x4 e0[3], e2[6];
        #pragma unroll
        for (int k = 0; k < 3; ++k) {                 // x1 chunk k: col group (t3+k)%3 (64%3==1)
            int i = (t3 + k) % 3;
            e0[k] = (i == 0) ? D0[0] : ((i == 1) ? D0[1] : D0[2]);
        }
        #pragma unroll
        for (int k = 0; k < 6; ++k) {                 // x2 chunk k: col group (t6+4k)%6 (64%6==4)
            int i = (t6 + 4 * k) % 6;
            e2[k] = (i == 0) ? D2[0] : ((i == 1) ? D2[1] : ((i == 2) ? D2[2] :
                    ((i == 3) ? D2[3] : ((i == 4) ? D2[4] : D2[5]))));
        }

        const float4* p1 = (const float4*)x1;
        const float4* p2 = (const float4*)x2;
        float4*       q0 = (float4*)s0out;
        float4*       q1 = (float4*)s1out;
        const size_t  n1 = (size_t)B * 3;
        const size_t  n2 = (size_t)B * 6;
        const float4  z  = make_float4(0.f, 0.f, 0.f, 0.f);

        auto loadTile = [&](float4* buf, int t) {
            const size_t b1 = (size_t)t * 768  + (size_t)w * 192;
            const size_t b2 = (size_t)t * 1536 + (size_t)w * 384;
            #pragma unroll
            for (int k = 0; k < 3; ++k) { size_t i = b1 + k * 64 + l; buf[k]     = (i < n1) ? p1[i] : z; }
            #pragma unroll
            for (int k = 0; k < 6; ++k) { size_t i = b2 + k * 64 + l; buf[3 + k] = (i < n2) ? p2[i] : z; }
        };

        auto processTile = [&](const float4* buf, int t) {
            const size_t b1 = (size_t)t * 768  + (size_t)w * 192;
            const size_t b2 = (size_t)t * 1536 + (size_t)w * 384;
            // x1 -> s0 spikes: contiguous stores + LDS scatter to aTw rows 0..11.
            #pragma unroll
            for (int k = 0; k < 3; ++k) {
                int q = k * 64 + l;
                int r = q / 3;
                int c = 4 * (q - 3 * r);
                float4 v = buf[k];
                f32x4  e = e0[k];
                float sa = (v.x * e[0] > 0.5f) ? 1.f : 0.f;
                float sb = (v.y * e[1] > 0.5f) ? 1.f : 0.f;
                float sc = (v.z * e[2] > 0.5f) ? 1.f : 0.f;
                float sd = (v.w * e[3] > 0.5f) ? 1.f : 0.f;
                size_t gi = b1 + q;
                if (gi < n1) q0[gi] = make_float4(sa, sb, sc, sd);
                aTw[(c + 0) * LDSS + r] = (__bf16)sa;
                aTw[(c + 1) * LDSS + r] = (__bf16)sb;
                aTw[(c + 2) * LDSS + r] = (__bf16)sc;
                aTw[(c + 3) * LDSS + r] = (__bf16)sd;
            }
            // x2 -> s1 spikes + x2 values: aTw rows 12..35 (vals), bTw rows 0..23 (spikes).
            #pragma unroll
            for (int k = 0; k < 6; ++k) {
                int q = k * 64 + l;
                int r = q / 6;
                int c = 4 * (q - 6 * r);
                float4 v = buf[3 + k];
                f32x4  e = e2[k];
                float sa = (v.x * e[0] > 0.5f) ? 1.f : 0.f;
                float sb = (v.y * e[1] > 0.5f) ? 1.f : 0.f;
                float sc = (v.z * e[2] > 0.5f) ? 1.f : 0.f;
                float sd = (v.w * e[3] > 0.5f) ? 1.f : 0.f;
                size_t gi = b2 + q;
                if (gi < n2) q1[gi] = make_float4(sa, sb, sc, sd);
                aTw[(12 + c + 0) * LDSS + r] = (__bf16)v.x;
                aTw[(12 + c + 1) * LDSS + r] = (__bf16)v.y;
                aTw[(12 + c + 2) * LDSS + r] = (__bf16)v.z;
                aTw[(12 + c + 3) * LDSS + r] = (__bf16)v.w;
                bTw[(c + 0) * LDSS + r] = (__bf16)sa;
                bTw[(c + 1) * LDSS + r] = (__bf16)sb;
                bTw[(c + 2) * LDSS + r] = (__bf16)sc;
                bTw[(c + 3) * LDSS + r] = (__bf16)sd;
            }
            mfmaPhase();   // wave-private; DS in-order per wave, compiler inserts counted waits
        };

        // Per-wave depth-1 register prefetch: loads of t+1 issue BEFORE stores of t,
        // so counted vmcnt never waits on store retirement (in-order vmcnt FIFO).
        int t = t0;
        float4 bufA[9], bufB[9];
        if (t < t1) loadTile(bufA, t);
        while (t < t1) {
            int tn = t + 1;
            if (tn < t1) loadTile(bufB, tn);
            processTile(bufA, t);
            t = tn;
            if (t >= t1) break;
            tn = t + 1;
            if (tn < t1) loadTile(bufA, tn);
            processTile(bufB, t);
            t = tn;
        }
    } else {
        // Generic fallback: one row per lane, wave-private staging, no barriers.
        for (int t = t0; t < t1; ++t) {
            long r = (long)t * 256 + w * 64 + l;
            bool v = r < B;
            float xv[36];
            const float4 z = make_float4(0.f, 0.f, 0.f, 0.f);
            const float4* p1 = (const float4*)(x1 + r * 12);
            const float4* p2 = (const float4*)(x2 + r * 24);
            #pragma unroll
            for (int c = 0; c < 3; ++c) {
                float4 t4 = v ? p1[c] : z;
                xv[4*c+0] = t4.x; xv[4*c+1] = t4.y; xv[4*c+2] = t4.z; xv[4*c+3] = t4.w;
            }
            #pragma unroll
            for (int c = 0; c < 6; ++c) {
                float4 t4 = v ? p2[c] : z;
                xv[12+4*c+0] = t4.x; xv[12+4*c+1] = t4.y; xv[12+4*c+2] = t4.z; xv[12+4*c+3] = t4.w;
            }
            float s0v[12], s1v[24];
            #pragma unroll 1
            for (int j = 0; j < 12; ++j) {
                float a = 0.0f;
                for (int k = 0; k < 12; ++k) a += xv[k] * W0[k * 12 + j];
                s0v[j] = (a > 0.5f) ? 1.0f : 0.0f;
            }
            #pragma unroll 1
            for (int j = 0; j < 24; ++j) {
                float a = 0.0f;
                for (int k = 0; k < 12; ++k) a += s0v[k] * W1[k * 24 + j];
                for (int k = 0; k < 24; ++k) a += xv[12 + k] * W2[k * 24 + j];
                s1v[j] = (a > 0.5f) ? 1.0f : 0.0f;
            }
            if (v) {
                float4* q0 = (float4*)(s0out + (size_t)r * 12);
                q0[0] = make_float4(s0v[0], s0v[1], s0v[2],  s0v[3]);
                q0[1] = make_float4(s0v[4], s0v[5], s0v[6],  s0v[7]);
                q0[2] = make_float4(s0v[8], s0v[9], s0v[10], s0v[11]);
                float4* q1 = (float4*)(s1out + (size_t)r * 24);
                #pragma unroll
                for (int c = 0; c < 6; ++c)
                    q1[c] = make_float4(s1v[4*c+0], s1v[4*c+1], s1v[4*c+2], s1v[4*c+3]);
            }
            #pragma unroll
            for (int m = 0; m < 12; ++m) aTw[m * LDSS + l]        = (__bf16)(v ? s0v[m] : 0.f);
            #pragma unroll
            for (int m = 0; m < 24; ++m) aTw[(12 + m) * LDSS + l] = (__bf16)(v ? xv[12 + m] : 0.f);
            #pragma unroll
            for (int n = 0; n < 24; ++n) bTw[n * LDSS + l]        = (__bf16)(v ? s1v[n] : 0.f);
            mfmaPhase();
        }
    }

    // Block-level reduction of the 4 waves' identical position sets, then 864 atomics/block.
    __syncthreads();
    float* red = (float*)aT;   // 4*6*256 floats = 24KB, fits in aT region
    #pragma unroll
    for (int p = 0; p < 6; ++p)
        *(f32x4*)&red[(w * 6 + p) * 256 + l * 4] = acc[p];
    __syncthreads();
    for (int e = tid; e < 1536; e += TPB) {
        int p  = e >> 8, le = e & 255;
        float s = red[p * 256 + le] + red[(6 + p) * 256 + le]
                + red[(12 + p) * 256 + le] + red[(18 + p) * 256 + le];
        int lane = le >> 2, i = le & 3;
        int m = (p % 3) * 16 + (lane >> 4) * 4 + i;
        int n = (p / 3) * 16 + (lane & 15);
        if (m < 36 && n < 24) {
            int addr = (m < 12) ? (m * 24 + n) : (288 + (m - 12) * 24 + n);
            atomicAdd(out + addr, s);
        }
    }
}

extern "C" void kernel_launch(void* const* d_in, const int* in_sizes, int n_in,
                              void* d_out, int out_size, void* d_ws, size_t ws_size,
                              hipStream_t stream) {
    const float* x1 = (const float*)d_in[0];
    const float* x2 = (const float*)d_in[1];
    const float* W0 = (const float*)d_in[2];
    const float* W1 = (const float*)d_in[3];
    const float* W2 = (const float*)d_in[4];
    float* out = (float*)d_out;
    const int B = in_sizes[0] / 12;
    if (B <= 0) return;

    zero_dw_kernel<<<dim3(4), dim3(256), 0, stream>>>(out);
    bnesnn_kernel<<<dim3(768), dim3(TPB), 0, stream>>>(x1, x2, W0, W1, W2, out, B);
}

// Round 14
// 165.648 us; speedup vs baseline: 1.0460x; 1.0460x over previous
//
#include <hip/hip_runtime.h>

// Output layout: dw1[12][24] at out[0..288), dw2[24][24] at out[288..864),
// s0[B][12] at out+864, s1[B][24] after s0.

typedef __bf16 bf16x8 __attribute__((ext_vector_type(8)));
typedef float  f32x4  __attribute__((ext_vector_type(4)));

constexpr int TPB = 256;           // 4 waves; each wave owns 64 rows per block-tile
constexpr int LDSS = 72;           // LDS row stride (elems): 144B, conflict-benign frag reads

__global__ void zero_dw_kernel(float* out) {
    int t = threadIdx.x + blockIdx.x * blockDim.x;
    if (t < 864) out[t] = 0.0f;
}

__global__ __launch_bounds__(TPB, 3)
void bnesnn_kernel(const float* __restrict__ x1, const float* __restrict__ x2,
                   const float* __restrict__ W0, const float* __restrict__ W1,
                   const float* __restrict__ W2, float* __restrict__ out, int B)
{
    // Per-wave private slices: aT rows 0..11 = s0 spikes, 12..35 = x2 vals, 36..47 = pad;
    // bT rows 0..23 = s1 spikes, 24..31 = pad. No cross-wave coupling -> no loop barriers.
    __shared__ __attribute__((aligned(16))) __bf16 aT[4 * 48 * LDSS];
    __shared__ __attribute__((aligned(16))) __bf16 bT[4 * 32 * LDSS];

    const int tid = threadIdx.x;
    const int w   = tid >> 6;
    const int l   = tid & 63;
    __bf16* aTw = aT + w * 48 * LDSS;
    __bf16* bTw = bT + w * 32 * LDSS;

    for (int i = l; i < 12 * LDSS; i += 64) aTw[36 * LDSS + i] = (__bf16)0.0f;
    for (int i = l; i <  8 * LDSS; i += 64) bTw[24 * LDSS + i] = (__bf16)0.0f;

    // Structure detection: W0 diag, W1 zero, W2 diag (uniform, deterministic).
    bool okv = true;
    for (int i = tid; i < 144; i += TPB) if ((i / 12) != (i % 12) && W0[i] != 0.0f) okv = false;
    for (int i = tid; i < 288; i += TPB) if (W1[i] != 0.0f) okv = false;
    for (int i = tid; i < 576; i += TPB) if ((i / 24) != (i % 24) && W2[i] != 0.0f) okv = false;
    const int fast = __syncthreads_and(okv ? 1 : 0);

    float* s0out = out + 864;
    float* s1out = out + 864 + (size_t)12 * B;

    const int lrow = l & 15;
    const int kb   = (l >> 4) * 8;

    f32x4 acc[6] = {};

    const int NT = (B + 255) / 256;

    auto mfmaPhase = [&]() {
        #pragma unroll
        for (int p = 0; p < 6; ++p) {
            const int mt = p % 3, nt = p / 3;
            const int ar = (mt * 16 + lrow) * LDSS + kb;
            const int br = (nt * 16 + lrow) * LDSS + kb;
            #pragma unroll
            for (int kk = 0; kk < 64; kk += 32) {
                bf16x8 af = *(const bf16x8*)&aTw[ar + kk];
                bf16x8 bf = *(const bf16x8*)&bTw[br + kk];
                acc[p] = __builtin_amdgcn_mfma_f32_16x16x32_bf16(af, bf, acc[p], 0, 0, 0);
            }
        }
    };

    if (fast) {
        // Diagonal chunk vectors (uniform scalar loads), then per-lane selection.
        f32x4 D0[3], D2[6];
        #pragma unroll
        for (int c = 0; c < 3; ++c) {
            D0[c][0] = W0[(4*c+0)*13]; D0[c][1] = W0[(4*c+1)*13];
            D0[c][2] = W0[(4*c+2)*13]; D0[c][3] = W0[(4*c+3)*13];
        }
        #pragma unroll
        for (int c = 0; c < 6; ++c) {
            D2[c][0] = W2[(4*c+0)*25]; D2[c][1] = W2[(4*c+1)*25];
            D2[c][2] = W2[(4*c+2)*25]; D2[c][3] = W2[(4*c+3)*25];
        }
        const int t3 = l % 3, t6 = l % 6;
        f32x4 e0[3], e2[6];
        #pragma unroll
        for (int k = 0; k < 3; ++k) {                 // x1 chunk k: col group (t3+k)%3 (64%3==1)
            int i = (t3 + k) % 3;
            e0[k] = (i == 0) ? D0[0] : ((i == 1) ? D0[1] : D0[2]);
        }
        #pragma unroll
        for (int k = 0; k < 6; ++k) {                 // x2 chunk k: col group (t6+4k)%6 (64%6==4)
            int i = (t6 + 4 * k) % 6;
            e2[k] = (i == 0) ? D2[0] : ((i == 1) ? D2[1] : ((i == 2) ? D2[2] :
                    ((i == 3) ? D2[3] : ((i == 4) ? D2[4] : D2[5]))));
        }

        const float4* p1 = (const float4*)x1;
        const float4* p2 = (const float4*)x2;
        float4*       q0 = (float4*)s0out;
        float4*       q1 = (float4*)s1out;
        const size_t  n1 = (size_t)B * 3;
        const size_t  n2 = (size_t)B * 6;
        const float4  z  = make_float4(0.f, 0.f, 0.f, 0.f);

// Spill-proof prefetch: named float4 variables only (no arrays, no pointer-passing).
#define LOADT(P, tt) { \
        const size_t b1 = (size_t)(tt) * 768  + (size_t)w * 192; \
        const size_t b2 = (size_t)(tt) * 1536 + (size_t)w * 384; \
        size_t i0_ = b1 + 0 * 64 + l; P##0 = (i0_ < n1) ? p1[i0_] : z; \
        size_t i1_ = b1 + 1 * 64 + l; P##1 = (i1_ < n1) ? p1[i1_] : z; \
        size_t i2_ = b1 + 2 * 64 + l; P##2 = (i2_ < n1) ? p1[i2_] : z; \
        size_t i3_ = b2 + 0 * 64 + l; P##3 = (i3_ < n2) ? p2[i3_] : z; \
        size_t i4_ = b2 + 1 * 64 + l; P##4 = (i4_ < n2) ? p2[i4_] : z; \
        size_t i5_ = b2 + 2 * 64 + l; P##5 = (i5_ < n2) ? p2[i5_] : z; \
        size_t i6_ = b2 + 3 * 64 + l; P##6 = (i6_ < n2) ? p2[i6_] : z; \
        size_t i7_ = b2 + 4 * 64 + l; P##7 = (i7_ < n2) ? p2[i7_] : z; \
        size_t i8_ = b2 + 5 * 64 + l; P##8 = (i8_ < n2) ? p2[i8_] : z; }

#define SPK1(P, k) { \
        int q_ = (k) * 64 + l; int r_ = q_ / 3; int c_ = 4 * (q_ - 3 * r_); \
        float sa_ = (P.x * e0[k][0] > 0.5f) ? 1.f : 0.f; \
        float sb_ = (P.y * e0[k][1] > 0.5f) ? 1.f : 0.f; \
        float sc_ = (P.z * e0[k][2] > 0.5f) ? 1.f : 0.f; \
        float sd_ = (P.w * e0[k][3] > 0.5f) ? 1.f : 0.f; \
        size_t gi_ = b1_ + q_; \
        if (gi_ < n1) q0[gi_] = make_float4(sa_, sb_, sc_, sd_); \
        aTw[(c_ + 0) * LDSS + r_] = (__bf16)sa_; \
        aTw[(c_ + 1) * LDSS + r_] = (__bf16)sb_; \
        aTw[(c_ + 2) * LDSS + r_] = (__bf16)sc_; \
        aTw[(c_ + 3) * LDSS + r_] = (__bf16)sd_; }

#define SPK2(P, k) { \
        int q_ = (k) * 64 + l; int r_ = q_ / 6; int c_ = 4 * (q_ - 6 * r_); \
        float sa_ = (P.x * e2[k][0] > 0.5f) ? 1.f : 0.f; \
        float sb_ = (P.y * e2[k][1] > 0.5f) ? 1.f : 0.f; \
        float sc_ = (P.z * e2[k][2] > 0.5f) ? 1.f : 0.f; \
        float sd_ = (P.w * e2[k][3] > 0.5f) ? 1.f : 0.f; \
        size_t gi_ = b2_ + q_; \
        if (gi_ < n2) q1[gi_] = make_float4(sa_, sb_, sc_, sd_); \
        aTw[(12 + c_ + 0) * LDSS + r_] = (__bf16)P.x; \
        aTw[(12 + c_ + 1) * LDSS + r_] = (__bf16)P.y; \
        aTw[(12 + c_ + 2) * LDSS + r_] = (__bf16)P.z; \
        aTw[(12 + c_ + 3) * LDSS + r_] = (__bf16)P.w; \
        bTw[(c_ + 0) * LDSS + r_] = (__bf16)sa_; \
        bTw[(c_ + 1) * LDSS + r_] = (__bf16)sb_; \
        bTw[(c_ + 2) * LDSS + r_] = (__bf16)sc_; \
        bTw[(c_ + 3) * LDSS + r_] = (__bf16)sd_; }

#define PROCT(P, tt) { \
        const size_t b1_ = (size_t)(tt) * 768  + (size_t)w * 192; \
        const size_t b2_ = (size_t)(tt) * 1536 + (size_t)w * 384; \
        SPK1(P##0, 0) SPK1(P##1, 1) SPK1(P##2, 2) \
        SPK2(P##3, 0) SPK2(P##4, 1) SPK2(P##5, 2) \
        SPK2(P##6, 3) SPK2(P##7, 4) SPK2(P##8, 5) \
        mfmaPhase(); }

        float4 pA0, pA1, pA2, pA3, pA4, pA5, pA6, pA7, pA8;
        float4 pB0, pB1, pB2, pB3, pB4, pB5, pB6, pB7, pB8;

        // Grid-stride with depth-1 prefetch: loads of t+stride issue BEFORE
        // processing of t, so each wave keeps 9KB outstanding during compute
        // (Little's law: raises avg in-flight bytes ~10x vs load-wait-process).
        const int stride = gridDim.x;
        int t = blockIdx.x;
        if (t < NT) LOADT(pA, t)
        while (t < NT) {
            int tn = t + stride;
            if (tn < NT) LOADT(pB, tn)
            PROCT(pA, t)
            t = tn;
            if (t >= NT) break;
            tn = t + stride;
            if (tn < NT) LOADT(pA, tn)
            PROCT(pB, t)
            t = tn;
        }
#undef LOADT
#undef SPK1
#undef SPK2
#undef PROCT
    } else {
        // Generic fallback: one row per lane, wave-private staging, no barriers.
        for (int t = blockIdx.x; t < NT; t += gridDim.x) {
            long r = (long)t * 256 + w * 64 + l;
            bool v = r < B;
            float xv[36];
            const float4 z = make_float4(0.f, 0.f, 0.f, 0.f);
            const float4* p1 = (const float4*)(x1 + r * 12);
            const float4* p2 = (const float4*)(x2 + r * 24);
            #pragma unroll
            for (int c = 0; c < 3; ++c) {
                float4 t4 = v ? p1[c] : z;
                xv[4*c+0] = t4.x; xv[4*c+1] = t4.y; xv[4*c+2] = t4.z; xv[4*c+3] = t4.w;
            }
            #pragma unroll
            for (int c = 0; c < 6; ++c) {
                float4 t4 = v ? p2[c] : z;
                xv[12+4*c+0] = t4.x; xv[12+4*c+1] = t4.y; xv[12+4*c+2] = t4.z; xv[12+4*c+3] = t4.w;
            }
            float s0v[12], s1v[24];
            #pragma unroll 1
            for (int j = 0; j < 12; ++j) {
                float a = 0.0f;
                for (int k = 0; k < 12; ++k) a += xv[k] * W0[k * 12 + j];
                s0v[j] = (a > 0.5f) ? 1.0f : 0.0f;
            }
            #pragma unroll 1
            for (int j = 0; j < 24; ++j) {
                float a = 0.0f;
                for (int k = 0; k < 12; ++k) a += s0v[k] * W1[k * 24 + j];
                for (int k = 0; k < 24; ++k) a += xv[12 + k] * W2[k * 24 + j];
                s1v[j] = (a > 0.5f) ? 1.0f : 0.0f;
            }
            if (v) {
                float4* q0 = (float4*)(s0out + (size_t)r * 12);
                q0[0] = make_float4(s0v[0], s0v[1], s0v[2],  s0v[3]);
                q0[1] = make_float4(s0v[4], s0v[5], s0v[6],  s0v[7]);
                q0[2] = make_float4(s0v[8], s0v[9], s0v[10], s0v[11]);
                float4* q1 = (float4*)(s1out + (size_t)r * 24);
                #pragma unroll
                for (int c = 0; c < 6; ++c)
                    q1[c] = make_float4(s1v[4*c+0], s1v[4*c+1], s1v[4*c+2], s1v[4*c+3]);
            }
            #pragma unroll
            for (int m = 0; m < 12; ++m) aTw[m * LDSS + l]        = (__bf16)(v ? s0v[m] : 0.f);
            #pragma unroll
            for (int m = 0; m < 24; ++m) aTw[(12 + m) * LDSS + l] = (__bf16)(v ? xv[12 + m] : 0.f);
            #pragma unroll
            for (int n = 0; n < 24; ++n) bTw[n * LDSS + l]        = (__bf16)(v ? s1v[n] : 0.f);
            mfmaPhase();
        }
    }

    // Block-level reduction of the 4 waves' identical position sets, then 864 atomics/block.
    __syncthreads();
    float* red = (float*)aT;   // 4*6*256 floats = 24KB, fits in aT region
    #pragma unroll
    for (int p = 0; p < 6; ++p)
        *(f32x4*)&red[(w * 6 + p) * 256 + l * 4] = acc[p];
    __syncthreads();
    for (int e = tid; e < 1536; e += TPB) {
        int p  = e >> 8, le = e & 255;
        float s = red[p * 256 + le] + red[(6 + p) * 256 + le]
                + red[(12 + p) * 256 + le] + red[(18 + p) * 256 + le];
        int lane = le >> 2, i = le & 3;
        int m = (p % 3) * 16 + (lane >> 4) * 4 + i;
        int n = (p / 3) * 16 + (lane & 15);
        if (m < 36 && n < 24) {
            int addr = (m < 12) ? (m * 24 + n) : (288 + (m - 12) * 24 + n);
            atomicAdd(out + addr, s);
        }
    }
}

extern "C" void kernel_launch(void* const* d_in, const int* in_sizes, int n_in,
                              void* d_out, int out_size, void* d_ws, size_t ws_size,
                              hipStream_t stream) {
    const float* x1 = (const float*)d_in[0];
    const float* x2 = (const float*)d_in[1];
    const float* W0 = (const float*)d_in[2];
    const float* W1 = (const float*)d_in[3];
    const float* W2 = (const float*)d_in[4];
    float* out = (float*)d_out;
    const int B = in_sizes[0] / 12;
    if (B <= 0) return;

    zero_dw_kernel<<<dim3(4), dim3(256), 0, stream>>>(out);
    bnesnn_kernel<<<dim3(768), dim3(TPB), 0, stream>>>(x1, x2, W0, W1, W2, out, B);
}

// Round 15
// 117.298 us; speedup vs baseline: 1.4772x; 1.4122x over previous
//
#include <hip/hip_runtime.h>

// Output layout: dw1[12][24] at out[0..288), dw2[24][24] at out[288..864),
// s0[B][12] at out+864, s1[B][24] after s0.

typedef __bf16 bf16x8 __attribute__((ext_vector_type(8)));
typedef float  f32x4  __attribute__((ext_vector_type(4)));

constexpr int TPB  = 256;   // 4 waves; each wave owns 64 rows per block-tile
constexpr int LDSS = 72;    // LDS row stride (elems): 144B => 2-way max on frag reads (free)

__global__ void zero_dw_kernel(float* out) {
    int t = threadIdx.x + blockIdx.x * blockDim.x;
    if (t < 864) out[t] = 0.0f;
}

__global__ __launch_bounds__(TPB, 4)
void bnesnn_kernel(const float* __restrict__ x1, const float* __restrict__ x2,
                   const float* __restrict__ W0, const float* __restrict__ W1,
                   const float* __restrict__ W2, float* __restrict__ out, int B)
{
    // Carved shared memory (~34.8KB -> 4 blocks/CU = 16 waves/CU):
    //   per wave: aT 36 rows (0..11 s0 spikes, 12..35 x2 vals), bT 24 rows (s1 spikes)
    //   one shared 72-elem zero row serves ALL pad lanes (same-address broadcast).
    //   epilogue reduction (24KB) overlays the same region after a barrier.
    __shared__ __attribute__((aligned(16))) float smem4[8704];   // 34816 B
    __bf16* aT   = (__bf16*)smem4;                               // 4*36*72
    __bf16* bT   = (__bf16*)smem4 + 4 * 36 * LDSS;               // 4*24*72
    __bf16* zrow = (__bf16*)smem4 + 4 * 60 * LDSS;               // 72

    const int tid = threadIdx.x;
    const int w   = tid >> 6;
    const int l   = tid & 63;
    __bf16* aTw = aT + w * 36 * LDSS;
    __bf16* bTw = bT + w * 24 * LDSS;

    // Zero the shared pad row once (visible to all after the okv barrier).
    for (int i = tid; i < LDSS; i += TPB) zrow[i] = (__bf16)0.0f;

    // Structure detection: W0 diag, W1 zero, W2 diag (uniform, deterministic).
    bool okv = true;
    for (int i = tid; i < 144; i += TPB) if ((i / 12) != (i % 12) && W0[i] != 0.0f) okv = false;
    for (int i = tid; i < 288; i += TPB) if (W1[i] != 0.0f) okv = false;
    for (int i = tid; i < 576; i += TPB) if ((i / 24) != (i % 24) && W2[i] != 0.0f) okv = false;
    const int fast = __syncthreads_and(okv ? 1 : 0);

    float* s0out = out + 864;
    float* s1out = out + 864 + (size_t)12 * B;

    const int lrow = l & 15;
    const int kb   = (l >> 4) * 8;

    f32x4 acc[6] = {};

    const int NT = (B + 255) / 256;

    auto mfmaPhase = [&]() {
        #pragma unroll
        for (int p = 0; p < 6; ++p) {
            const int mt = p % 3, nt = p / 3;
            const int arow = mt * 16 + lrow;
            const int brow = nt * 16 + lrow;
            const __bf16* ap = (arow < 36) ? (aTw + arow * LDSS + kb) : (zrow + kb);
            const __bf16* bp = (brow < 24) ? (bTw + brow * LDSS + kb) : (zrow + kb);
            #pragma unroll
            for (int kk = 0; kk < 64; kk += 32) {
                bf16x8 af = *(const bf16x8*)(ap + kk);
                bf16x8 bf = *(const bf16x8*)(bp + kk);
                acc[p] = __builtin_amdgcn_mfma_f32_16x16x32_bf16(af, bf, acc[p], 0, 0, 0);
            }
        }
    };

    if (fast) {
        // Diagonal chunk vectors (uniform scalar loads), then per-lane selection.
        f32x4 D0[3], D2[6];
        #pragma unroll
        for (int c = 0; c < 3; ++c) {
            D0[c][0] = W0[(4*c+0)*13]; D0[c][1] = W0[(4*c+1)*13];
            D0[c][2] = W0[(4*c+2)*13]; D0[c][3] = W0[(4*c+3)*13];
        }
        #pragma unroll
        for (int c = 0; c < 6; ++c) {
            D2[c][0] = W2[(4*c+0)*25]; D2[c][1] = W2[(4*c+1)*25];
            D2[c][2] = W2[(4*c+2)*25]; D2[c][3] = W2[(4*c+3)*25];
        }
        const int t3 = l % 3, t6 = l % 6;
        f32x4 e0[3], e2[6];
        #pragma unroll
        for (int k = 0; k < 3; ++k) {                 // x1 chunk k: col group (t3+k)%3 (64%3==1)
            int i = (t3 + k) % 3;
            e0[k] = (i == 0) ? D0[0] : ((i == 1) ? D0[1] : D0[2]);
        }
        #pragma unroll
        for (int k = 0; k < 6; ++k) {                 // x2 chunk k: col group (t6+4k)%6 (64%6==4)
            int i = (t6 + 4 * k) % 6;
            e2[k] = (i == 0) ? D2[0] : ((i == 1) ? D2[1] : ((i == 2) ? D2[2] :
                    ((i == 3) ? D2[3] : ((i == 4) ? D2[4] : D2[5]))));
        }

        const float4* p1 = (const float4*)x1;
        const float4* p2 = (const float4*)x2;
        float4*       q0 = (float4*)s0out;
        float4*       q1 = (float4*)s1out;
        const size_t  n1 = (size_t)B * 3;
        const size_t  n2 = (size_t)B * 6;
        const float4  z  = make_float4(0.f, 0.f, 0.f, 0.f);

        for (int t = blockIdx.x; t < NT; t += gridDim.x) {
            const size_t b1 = (size_t)t * 768  + (size_t)w * 192;
            const size_t b2 = (size_t)t * 1536 + (size_t)w * 384;

            float4 buf[9];
            #pragma unroll
            for (int k = 0; k < 3; ++k) { size_t i = b1 + k * 64 + l; buf[k]     = (i < n1) ? p1[i] : z; }
            #pragma unroll
            for (int k = 0; k < 6; ++k) { size_t i = b2 + k * 64 + l; buf[3 + k] = (i < n2) ? p2[i] : z; }

            // x1 -> s0 spikes: contiguous stores + LDS scatter to aTw rows 0..11.
            #pragma unroll
            for (int k = 0; k < 3; ++k) {
                int q = k * 64 + l;
                int r = q / 3;
                int c = 4 * (q - 3 * r);
                float4 v = buf[k];
                f32x4  e = e0[k];
                float sa = (v.x * e[0] > 0.5f) ? 1.f : 0.f;
                float sb = (v.y * e[1] > 0.5f) ? 1.f : 0.f;
                float sc = (v.z * e[2] > 0.5f) ? 1.f : 0.f;
                float sd = (v.w * e[3] > 0.5f) ? 1.f : 0.f;
                size_t gi = b1 + q;
                if (gi < n1) q0[gi] = make_float4(sa, sb, sc, sd);
                aTw[(c + 0) * LDSS + r] = (__bf16)sa;
                aTw[(c + 1) * LDSS + r] = (__bf16)sb;
                aTw[(c + 2) * LDSS + r] = (__bf16)sc;
                aTw[(c + 3) * LDSS + r] = (__bf16)sd;
            }
            // x2 -> s1 spikes + x2 values: aTw rows 12..35 (vals), bTw rows 0..23 (spikes).
            #pragma unroll
            for (int k = 0; k < 6; ++k) {
                int q = k * 64 + l;
                int r = q / 6;
                int c = 4 * (q - 6 * r);
                float4 v = buf[3 + k];
                f32x4  e = e2[k];
                float sa = (v.x * e[0] > 0.5f) ? 1.f : 0.f;
                float sb = (v.y * e[1] > 0.5f) ? 1.f : 0.f;
                float sc = (v.z * e[2] > 0.5f) ? 1.f : 0.f;
                float sd = (v.w * e[3] > 0.5f) ? 1.f : 0.f;
                size_t gi = b2 + q;
                if (gi < n2) q1[gi] = make_float4(sa, sb, sc, sd);
                aTw[(12 + c + 0) * LDSS + r] = (__bf16)v.x;
                aTw[(12 + c + 1) * LDSS + r] = (__bf16)v.y;
                aTw[(12 + c + 2) * LDSS + r] = (__bf16)v.z;
                aTw[(12 + c + 3) * LDSS + r] = (__bf16)v.w;
                bTw[(c + 0) * LDSS + r] = (__bf16)sa;
                bTw[(c + 1) * LDSS + r] = (__bf16)sb;
                bTw[(c + 2) * LDSS + r] = (__bf16)sc;
                bTw[(c + 3) * LDSS + r] = (__bf16)sd;
            }
            mfmaPhase();   // wave-private; in-order lgkmcnt gives write->read ordering
        }
    } else {
        // Generic fallback: one row per lane, wave-private staging, no barriers.
        for (int t = blockIdx.x; t < NT; t += gridDim.x) {
            long r = (long)t * 256 + w * 64 + l;
            bool v = r < B;
            float xv[36];
            const float4 z = make_float4(0.f, 0.f, 0.f, 0.f);
            const float4* p1 = (const float4*)(x1 + r * 12);
            const float4* p2 = (const float4*)(x2 + r * 24);
            #pragma unroll
            for (int c = 0; c < 3; ++c) {
                float4 t4 = v ? p1[c] : z;
                xv[4*c+0] = t4.x; xv[4*c+1] = t4.y; xv[4*c+2] = t4.z; xv[4*c+3] = t4.w;
            }
            #pragma unroll
            for (int c = 0; c < 6; ++c) {
                float4 t4 = v ? p2[c] : z;
                xv[12+4*c+0] = t4.x; xv[12+4*c+1] = t4.y; xv[12+4*c+2] = t4.z; xv[12+4*c+3] = t4.w;
            }
            float s0v[12], s1v[24];
            #pragma unroll 1
            for (int j = 0; j < 12; ++j) {
                float a = 0.0f;
                for (int k = 0; k < 12; ++k) a += xv[k] * W0[k * 12 + j];
                s0v[j] = (a > 0.5f) ? 1.0f : 0.0f;
            }
            #pragma unroll 1
            for (int j = 0; j < 24; ++j) {
                float a = 0.0f;
                for (int k = 0; k < 12; ++k) a += s0v[k] * W1[k * 24 + j];
                for (int k = 0; k < 24; ++k) a += xv[12 + k] * W2[k * 24 + j];
                s1v[j] = (a > 0.5f) ? 1.0f : 0.0f;
            }
            if (v) {
                float4* q0 = (float4*)(s0out + (size_t)r * 12);
                q0[0] = make_float4(s0v[0], s0v[1], s0v[2],  s0v[3]);
                q0[1] = make_float4(s0v[4], s0v[5], s0v[6],  s0v[7]);
                q0[2] = make_float4(s0v[8], s0v[9], s0v[10], s0v[11]);
                float4* q1 = (float4*)(s1out + (size_t)r * 24);
                #pragma unroll
                for (int c = 0; c < 6; ++c)
                    q1[c] = make_float4(s1v[4*c+0], s1v[4*c+1], s1v[4*c+2], s1v[4*c+3]);
            }
            #pragma unroll
            for (int m = 0; m < 12; ++m) aTw[m * LDSS + l]        = (__bf16)(v ? s0v[m] : 0.f);
            #pragma unroll
            for (int m = 0; m < 24; ++m) aTw[(12 + m) * LDSS + l] = (__bf16)(v ? xv[12 + m] : 0.f);
            #pragma unroll
            for (int n = 0; n < 24; ++n) bTw[n * LDSS + l]        = (__bf16)(v ? s1v[n] : 0.f);
            mfmaPhase();
        }
    }

    // Block-level reduction of the 4 waves' identical position sets, then 864 atomics/block.
    __syncthreads();
    float* red = smem4;   // 24KB overlay, safe after barrier
    #pragma unroll
    for (int p = 0; p < 6; ++p)
        *(f32x4*)&red[(w * 6 + p) * 256 + l * 4] = acc[p];
    __syncthreads();
    for (int e = tid; e < 1536; e += TPB) {
        int p  = e >> 8, le = e & 255;
        float s = red[p * 256 + le] + red[(6 + p) * 256 + le]
                + red[(12 + p) * 256 + le] + red[(18 + p) * 256 + le];
        int lane = le >> 2, i = le & 3;
        int m = (p % 3) * 16 + (lane >> 4) * 4 + i;
        int n = (p / 3) * 16 + (lane & 15);
        if (m < 36 && n < 24) {
            int addr = (m < 12) ? (m * 24 + n) : (288 + (m - 12) * 24 + n);
            atomicAdd(out + addr, s);
        }
    }
}

extern "C" void kernel_launch(void* const* d_in, const int* in_sizes, int n_in,
                              void* d_out, int out_size, void* d_ws, size_t ws_size,
                              hipStream_t stream) {
    const float* x1 = (const float*)d_in[0];
    const float* x2 = (const float*)d_in[1];
    const float* W0 = (const float*)d_in[2];
    const float* W1 = (const float*)d_in[3];
    const float* W2 = (const float*)d_in[4];
    float* out = (float*)d_out;
    const int B = in_sizes[0] / 12;
    if (B <= 0) return;

    zero_dw_kernel<<<dim3(4), dim3(256), 0, stream>>>(out);
    bnesnn_kernel<<<dim3(1024), dim3(TPB), 0, stream>>>(x1, x2, W0, W1, W2, out, B);
}

// Round 16
// 69.697 us; speedup vs baseline: 2.4860x; 1.6830x over previous
//
#include <hip/hip_runtime.h>

// Output layout: dw1[12][24] at out[0..288), dw2[24][24] at out[288..864),
// s0[B][12] at out+864, s1[B][24] after s0.

typedef __bf16 bf16x8 __attribute__((ext_vector_type(8)));
typedef float  f32x4  __attribute__((ext_vector_type(4)));

constexpr int TPB  = 256;   // 4 waves, wave-private pipelines
constexpr int LDSS = 72;    // staging row stride (elems): 144B, conflict-benign

__global__ void zero_dw_kernel(float* out) {
    int t = threadIdx.x + blockIdx.x * blockDim.x;
    if (t < 864) out[t] = 0.0f;
}

// Async global->LDS DMA, 16B per lane. LDS dest is wave-uniform base + lane*16.
__device__ __forceinline__ void gload16(const float* g, float* lds) {
    __builtin_amdgcn_global_load_lds(
        (const __attribute__((address_space(1))) void*)(const void*)g,
        (__attribute__((address_space(3))) void*)(void*)lds, 16, 0, 0);
}

__global__ __launch_bounds__(TPB, 1)
void bnesnn_kernel(const float* __restrict__ x1, const float* __restrict__ x2,
                   const float* __restrict__ W0, const float* __restrict__ W1,
                   const float* __restrict__ W2, float* __restrict__ out, int B)
{
    // Per-wave: double-buffered raw-x DMA target (2x9KB) + bf16 staging tiles.
    // Total ~108.4KB -> 1 block/CU (intentional: waves should be BW-bound).
    __shared__ __attribute__((aligned(16))) float  xsh[4][2][2304];   // 73728B
    __shared__ __attribute__((aligned(16))) __bf16 aTs[4][36 * LDSS]; // 20736B
    __shared__ __attribute__((aligned(16))) __bf16 bTs[4][24 * LDSS]; // 13824B
    __shared__ __attribute__((aligned(16))) __bf16 zrow[LDSS];        // 144B

    const int tid = threadIdx.x;
    const int w   = tid >> 6;
    const int l   = tid & 63;
    __bf16* aTw = aTs[w];
    __bf16* bTw = bTs[w];

    for (int i = tid; i < LDSS; i += TPB) zrow[i] = (__bf16)0.0f;

    // Structure detection: W0 diag, W1 zero, W2 diag (uniform, deterministic).
    bool okv = true;
    for (int i = tid; i < 144; i += TPB) if ((i / 12) != (i % 12) && W0[i] != 0.0f) okv = false;
    for (int i = tid; i < 288; i += TPB) if (W1[i] != 0.0f) okv = false;
    for (int i = tid; i < 576; i += TPB) if ((i / 24) != (i % 24) && W2[i] != 0.0f) okv = false;
    const int wdiag = __syncthreads_and(okv ? 1 : 0);
    const int fast  = wdiag && ((B & 255) == 0);   // DMA path assumes full 256-row tiles

    float* s0out = out + 864;
    float* s1out = out + 864 + (size_t)12 * B;

    const int lrow = l & 15;
    const int kb   = (l >> 4) * 8;

    f32x4 acc[6] = {};

    const int NT = (B + 255) / 256;
    const int grid = gridDim.x;
    const int qn = NT / grid, rn = NT % grid;
    const int bid = blockIdx.x;
    const int t0  = (bid < rn) ? bid * (qn + 1) : rn * (qn + 1) + (bid - rn) * qn;
    const int t1  = t0 + ((bid < rn) ? qn + 1 : qn);

    auto mfmaPhase = [&]() {
        #pragma unroll
        for (int p = 0; p < 6; ++p) {
            const int mt = p % 3, nt = p / 3;
            const int arow = mt * 16 + lrow;
            const int brow = nt * 16 + lrow;
            const __bf16* ap = (arow < 36) ? (aTw + arow * LDSS + kb) : (zrow + kb);
            const __bf16* bp = (brow < 24) ? (bTw + brow * LDSS + kb) : (zrow + kb);
            #pragma unroll
            for (int kk = 0; kk < 64; kk += 32) {
                bf16x8 af = *(const bf16x8*)(ap + kk);
                bf16x8 bf = *(const bf16x8*)(bp + kk);
                acc[p] = __builtin_amdgcn_mfma_f32_16x16x32_bf16(af, bf, acc[p], 0, 0, 0);
            }
        }
    };

    if (fast) {
        // Diagonal chunk vectors (uniform scalar loads), then per-lane selection.
        f32x4 D0[3], D2[6];
        #pragma unroll
        for (int c = 0; c < 3; ++c) {
            D0[c][0] = W0[(4*c+0)*13]; D0[c][1] = W0[(4*c+1)*13];
            D0[c][2] = W0[(4*c+2)*13]; D0[c][3] = W0[(4*c+3)*13];
        }
        #pragma unroll
        for (int c = 0; c < 6; ++c) {
            D2[c][0] = W2[(4*c+0)*25]; D2[c][1] = W2[(4*c+1)*25];
            D2[c][2] = W2[(4*c+2)*25]; D2[c][3] = W2[(4*c+3)*25];
        }
        const int t3 = l % 3, t6 = l % 6;
        f32x4 e0[3], e2[6];
        #pragma unroll
        for (int k = 0; k < 3; ++k) {
            int i = (t3 + k) % 3;
            e0[k] = (i == 0) ? D0[0] : ((i == 1) ? D0[1] : D0[2]);
        }
        #pragma unroll
        for (int k = 0; k < 6; ++k) {
            int i = (t6 + 4 * k) % 6;
            e2[k] = (i == 0) ? D2[0] : ((i == 1) ? D2[1] : ((i == 2) ? D2[2] :
                    ((i == 3) ? D2[3] : ((i == 4) ? D2[4] : D2[5]))));
        }

        float4* q0 = (float4*)s0out;
        float4* q1 = (float4*)s1out;
        float*  xw0 = &xsh[w][0][0];
        float*  xw1 = &xsh[w][1][0];

        // Issue 9 DMA chunk-loads for tile tt into buffer dd (wave-uniform dest).
        auto issueTile = [&](int tt, int dd) {
            const size_t b1 = (size_t)tt * 768  + (size_t)w * 192;   // float4 units
            const size_t b2 = (size_t)tt * 1536 + (size_t)w * 384;
            float* dst = dd ? xw1 : xw0;
            const float* g1 = x1 + (b1 + (size_t)l) * 4;   // per-lane global src
            const float* g2 = x2 + (b2 + (size_t)l) * 4;
            #pragma unroll
            for (int k = 0; k < 3; ++k) gload16(g1 + k * 256, dst + k * 256);
            #pragma unroll
            for (int k = 0; k < 6; ++k) gload16(g2 + k * 256, dst + 768 + k * 256);
        };

        if (t0 < t1) issueTile(t0, 0);
        for (int t = t0, d = 0; t < t1; ++t, d ^= 1) {
            if (t + 1 < t1) {
                issueTile(t + 1, d ^ 1);
                // Oldest 9 = this tile's DMA; keep the 9 prefetch loads in flight.
                asm volatile("s_waitcnt vmcnt(9)" ::: "memory");
            } else {
                asm volatile("s_waitcnt vmcnt(0)" ::: "memory");
            }
            __builtin_amdgcn_sched_barrier(0);

            const float* xb = d ? xw1 : xw0;
            float4 buf[9];
            #pragma unroll
            for (int k = 0; k < 9; ++k) buf[k] = *(const float4*)&xb[k * 256 + l * 4];

            const size_t b1 = (size_t)t * 768  + (size_t)w * 192;
            const size_t b2 = (size_t)t * 1536 + (size_t)w * 384;

            // x1 -> s0 spikes: contiguous stores + LDS scatter to aTw rows 0..11.
            #pragma unroll
            for (int k = 0; k < 3; ++k) {
                int q = k * 64 + l;
                int r = q / 3;
                int c = 4 * (q - 3 * r);
                float4 v = buf[k];
                f32x4  e = e0[k];
                float sa = (v.x * e[0] > 0.5f) ? 1.f : 0.f;
                float sb = (v.y * e[1] > 0.5f) ? 1.f : 0.f;
                float sc = (v.z * e[2] > 0.5f) ? 1.f : 0.f;
                float sd = (v.w * e[3] > 0.5f) ? 1.f : 0.f;
                q0[b1 + q] = make_float4(sa, sb, sc, sd);
                aTw[(c + 0) * LDSS + r] = (__bf16)sa;
                aTw[(c + 1) * LDSS + r] = (__bf16)sb;
                aTw[(c + 2) * LDSS + r] = (__bf16)sc;
                aTw[(c + 3) * LDSS + r] = (__bf16)sd;
            }
            // x2 -> s1 spikes + x2 values: aTw rows 12..35 (vals), bTw rows 0..23.
            #pragma unroll
            for (int k = 0; k < 6; ++k) {
                int q = k * 64 + l;
                int r = q / 6;
                int c = 4 * (q - 6 * r);
                float4 v = buf[3 + k];
                f32x4  e = e2[k];
                float sa = (v.x * e[0] > 0.5f) ? 1.f : 0.f;
                float sb = (v.y * e[1] > 0.5f) ? 1.f : 0.f;
                float sc = (v.z * e[2] > 0.5f) ? 1.f : 0.f;
                float sd = (v.w * e[3] > 0.5f) ? 1.f : 0.f;
                q1[b2 + q] = make_float4(sa, sb, sc, sd);
                aTw[(12 + c + 0) * LDSS + r] = (__bf16)v.x;
                aTw[(12 + c + 1) * LDSS + r] = (__bf16)v.y;
                aTw[(12 + c + 2) * LDSS + r] = (__bf16)v.z;
                aTw[(12 + c + 3) * LDSS + r] = (__bf16)v.w;
                bTw[(c + 0) * LDSS + r] = (__bf16)sa;
                bTw[(c + 1) * LDSS + r] = (__bf16)sb;
                bTw[(c + 2) * LDSS + r] = (__bf16)sc;
                bTw[(c + 3) * LDSS + r] = (__bf16)sd;
            }
            mfmaPhase();
        }
    } else {
        // Generic fallback: one row per lane, plain loads, any W / any B.
        for (int t = t0; t < t1; ++t) {
            long r = (long)t * 256 + w * 64 + l;
            bool v = r < B;
            float xv[36];
            const float4 z = make_float4(0.f, 0.f, 0.f, 0.f);
            const float4* p1 = (const float4*)(x1 + r * 12);
            const float4* p2 = (const float4*)(x2 + r * 24);
            #pragma unroll
            for (int c = 0; c < 3; ++c) {
                float4 t4 = v ? p1[c] : z;
                xv[4*c+0] = t4.x; xv[4*c+1] = t4.y; xv[4*c+2] = t4.z; xv[4*c+3] = t4.w;
            }
            #pragma unroll
            for (int c = 0; c < 6; ++c) {
                float4 t4 = v ? p2[c] : z;
                xv[12+4*c+0] = t4.x; xv[12+4*c+1] = t4.y; xv[12+4*c+2] = t4.z; xv[12+4*c+3] = t4.w;
            }
            float s0v[12], s1v[24];
            #pragma unroll 1
            for (int j = 0; j < 12; ++j) {
                float a = 0.0f;
                for (int k = 0; k < 12; ++k) a += xv[k] * W0[k * 12 + j];
                s0v[j] = (a > 0.5f) ? 1.0f : 0.0f;
            }
            #pragma unroll 1
            for (int j = 0; j < 24; ++j) {
                float a = 0.0f;
                for (int k = 0; k < 12; ++k) a += s0v[k] * W1[k * 24 + j];
                for (int k = 0; k < 24; ++k) a += xv[12 + k] * W2[k * 24 + j];
                s1v[j] = (a > 0.5f) ? 1.0f : 0.0f;
            }
            if (v) {
                float4* q0 = (float4*)(s0out + (size_t)r * 12);
                q0[0] = make_float4(s0v[0], s0v[1], s0v[2],  s0v[3]);
                q0[1] = make_float4(s0v[4], s0v[5], s0v[6],  s0v[7]);
                q0[2] = make_float4(s0v[8], s0v[9], s0v[10], s0v[11]);
                float4* q1 = (float4*)(s1out + (size_t)r * 24);
                #pragma unroll
                for (int c = 0; c < 6; ++c)
                    q1[c] = make_float4(s1v[4*c+0], s1v[4*c+1], s1v[4*c+2], s1v[4*c+3]);
            }
            #pragma unroll
            for (int m = 0; m < 12; ++m) aTw[m * LDSS + l]        = (__bf16)(v ? s0v[m] : 0.f);
            #pragma unroll
            for (int m = 0; m < 24; ++m) aTw[(12 + m) * LDSS + l] = (__bf16)(v ? xv[12 + m] : 0.f);
            #pragma unroll
            for (int n = 0; n < 24; ++n) bTw[n * LDSS + l]        = (__bf16)(v ? s1v[n] : 0.f);
            mfmaPhase();
        }
    }

    // Block-level reduction of the 4 waves' position sets, then 864 atomics/block.
    __syncthreads();
    float* red = &xsh[0][0][0];   // 24KB overlay, safe after barrier
    #pragma unroll
    for (int p = 0; p < 6; ++p)
        *(f32x4*)&red[(w * 6 + p) * 256 + l * 4] = acc[p];
    __syncthreads();
    for (int e = tid; e < 1536; e += TPB) {
        int p  = e >> 8, le = e & 255;
        float s = red[p * 256 + le] + red[(6 + p) * 256 + le]
                + red[(12 + p) * 256 + le] + red[(18 + p) * 256 + le];
        int lane = le >> 2, i = le & 3;
        int m = (p % 3) * 16 + (lane >> 4) * 4 + i;
        int n = (p / 3) * 16 + (lane & 15);
        if (m < 36 && n < 24) {
            int addr = (m < 12) ? (m * 24 + n) : (288 + (m - 12) * 24 + n);
            atomicAdd(out + addr, s);
        }
    }
}

extern "C" void kernel_launch(void* const* d_in, const int* in_sizes, int n_in,
                              void* d_out, int out_size, void* d_ws, size_t ws_size,
                              hipStream_t stream) {
    const float* x1 = (const float*)d_in[0];
    const float* x2 = (const float*)d_in[1];
    const float* W0 = (const float*)d_in[2];
    const float* W1 = (const float*)d_in[3];
    const float* W2 = (const float*)d_in[4];
    float* out = (float*)d_out;
    const int B = in_sizes[0] / 12;
    if (B <= 0) return;

    zero_dw_kernel<<<dim3(4), dim3(256), 0, stream>>>(out);
    bnesnn_kernel<<<dim3(256), dim3(TPB), 0, stream>>>(x1, x2, W0, W1, W2, out, B);
}